// Round 18
// baseline (76.049 us; speedup 1.0000x reference)
//
#include <hip/hip_runtime.h>
#include <math.h>

#define NPTS  10000
#define NS    79            // slices
#define SLICE 128           // 4 j-tiles of 32; NS*SLICE = 10112 (padded y)
#define NYP   (NS * SLICE)  // 10112
#define NYT   316           // y-tiles of 32 (= NS*4 exactly)
#define NXT   313           // real x-tiles of 32 (313*32 = 10016)
#define NXT2  320           // padded x-tiles (10*4*8) -> unguarded loads
#define CAND_EPS 2.5e-3f    // > 2x the split-bf16 approx error bound (~6e-4)

typedef __attribute__((ext_vector_type(8)))  short bf16x8;
typedef __attribute__((ext_vector_type(16))) float f32x16;

// round-to-nearest-even f32 -> bf16 bits, and exact bf16 -> f32
__device__ __forceinline__ unsigned short f2bf(float f) {
    const unsigned int b = __float_as_uint(f);
    return (unsigned short)((b + 0x7FFFu + ((b >> 16) & 1u)) >> 16);
}
__device__ __forceinline__ float bf2f(unsigned short u) {
    return __uint_as_float(((unsigned int)u) << 16);
}

// ---------------------------------------------------------------------------
// Pack pass (verified absmax 0.0 in R13-R15): MFMA operands, K=16, 11 slots.
// dot = xh*yh + xl*yh + xh*yl + hy, |err| <= ~6e-4. Layout:
// pk[c][tile][khalf][col32][8 u16]; lane fragment = one contiguous 16B chunk.
// Pad y rows: slot9 = bf16(-60000) -> never win. Pad x cols: clamped values,
// outputs masked on store.
// ---------------------------------------------------------------------------
__global__ __launch_bounds__(256) void pack_xy(
    const float* __restrict__ pred_pts, const float* __restrict__ targ_pts,
    unsigned short* __restrict__ ypk, unsigned short* __restrict__ xpk)
{
    const int idx = blockIdx.x * 256 + threadIdx.x;
    const int YTOT = 4 * NYP;
    if (idx < YTOT) {
        const int c = idx / NYP, j = idx - c * NYP;
        const int dir = c >> 1, b = c & 1;
        const float* yp = (dir == 0 ? pred_pts : targ_pts) + (size_t)b * NPTS * 3;
        unsigned short v[16];
#pragma unroll
        for (int e = 0; e < 16; ++e) v[e] = 0;
        if (j < NPTS) {
            const float a = yp[j*3+0], bb = yp[j*3+1], cc = yp[j*3+2];
            const float hy = -0.5f * fmaf(cc, cc, fmaf(bb, bb, a * a));
            const unsigned short ah = f2bf(a), bh = f2bf(bb), ch = f2bf(cc);
            v[0] = ah; v[1] = bh; v[2] = ch;
            v[3] = ah; v[4] = bh; v[5] = ch;
            v[6] = f2bf(a  - bf2f(ah));
            v[7] = f2bf(bb - bf2f(bh));
            v[8] = f2bf(cc - bf2f(ch));
            const unsigned short hh = f2bf(hy);
            v[9] = hh; v[10] = f2bf(hy - bf2f(hh));
        } else {
            v[9] = f2bf(-60000.0f);
        }
        const int jt = j >> 5, col = j & 31;
        unsigned short* d0 = ypk + ((((size_t)c*NYT + jt)*2 + 0)*32 + col)*8;
        unsigned short* d1 = ypk + ((((size_t)c*NYT + jt)*2 + 1)*32 + col)*8;
#pragma unroll
        for (int e = 0; e < 8; ++e) { d0[e] = v[e]; d1[e] = v[8+e]; }
    } else if (idx < YTOT + 4 * NXT2 * 32) {
        const int idx2 = idx - YTOT;
        const int c = idx2 / (NXT2*32), r = idx2 - c * (NXT2*32);
        const int dir = c >> 1, b = c & 1;
        const float* xp = (dir == 0 ? targ_pts : pred_pts) + (size_t)b * NPTS * 3;
        const int n = (r < NPTS) ? r : (NPTS - 1);     // clamp; store-masked later
        const float a = xp[n*3+0], bb = xp[n*3+1], cc = xp[n*3+2];
        unsigned short v[16];
#pragma unroll
        for (int e = 0; e < 16; ++e) v[e] = 0;
        const unsigned short ah = f2bf(a), bh = f2bf(bb), ch = f2bf(cc);
        v[0] = ah; v[1] = bh; v[2] = ch;
        v[3] = f2bf(a  - bf2f(ah));
        v[4] = f2bf(bb - bf2f(bh));
        v[5] = f2bf(cc - bf2f(ch));
        v[6] = ah; v[7] = bh; v[8] = ch;
        v[9] = f2bf(1.0f); v[10] = f2bf(1.0f);
        const int xt = r >> 5, col = r & 31;
        unsigned short* d0 = xpk + ((((size_t)c*NXT2 + xt)*2 + 0)*32 + col)*8;
        unsigned short* d1 = xpk + ((((size_t)c*NXT2 + xt)*2 + 1)*32 + col)*8;
#pragma unroll
        for (int e = 0; e < 8; ++e) { d0[e] = v[e]; d1[e] = v[8+e]; }
    }
}

// ---------------------------------------------------------------------------
// Pass A (MFMA v4): IDENTICAL structure to R15 but with __launch_bounds__
// (256,4) -> 128-VGPR budget. R14/R15 ran at VGPR=56 (default-bounds
// occupancy heuristic) and SPILLED the ~85 live regs to scratch: FETCH_SIZE
// was 7.6 GB/dispatch (vs ~0.1 GB of real operand traffic). This is the
// third appearance of the register-cap tax (R3/R9 scalar, R14/R15 MFMA).
// ---------------------------------------------------------------------------
__global__ __launch_bounds__(256, 4) void knn_mfma(
    const unsigned short* __restrict__ ypk,
    const unsigned short* __restrict__ xpk,
    float* __restrict__ wsM)
{
    const int c  = blockIdx.z;
    const int s  = blockIdx.y;
    const int wv = threadIdx.x >> 6;
    const int l  = threadIdx.x & 63;
    const int kh = l >> 5, col = l & 31;

    bf16x8 yf[4];
#pragma unroll
    for (int jt = 0; jt < 4; ++jt)
        yf[jt] = *(const bf16x8*)(ypk +
            ((((size_t)c*NYT + s*4 + jt)*2 + kh)*32 + col)*8);

    f32x16 zero;
#pragma unroll
    for (int i = 0; i < 16; ++i) zero[i] = 0.0f;

    const int xt0 = (blockIdx.x * 4 + wv) * 8;     // 8 x-tiles per wave
    const unsigned short* xbase = xpk + (((size_t)c*NXT2 + xt0)*2 + kh)*256 + col*8;

    bf16x8 xf = *(const bf16x8*)(xbase);           // tile xt0
#pragma unroll
    for (int t = 0; t < 8; ++t) {
        // prefetch next tile (pad guarantees in-bounds; result unused at t=7)
        const bf16x8 xfn = *(const bf16x8*)(xbase + (size_t)(t < 7 ? t + 1 : t) * 512);
        float m[4];
#pragma unroll
        for (int jt = 0; jt < 4; ++jt) {
            const f32x16 d =
                __builtin_amdgcn_mfma_f32_32x32x16_bf16(yf[jt], xf, zero, 0, 0, 0);
            const float u0 = fmaxf(fmaxf(d[0],  d[1]),  fmaxf(d[2],  d[3]));
            const float u1 = fmaxf(fmaxf(d[4],  d[5]),  fmaxf(d[6],  d[7]));
            const float u2 = fmaxf(fmaxf(d[8],  d[9]),  fmaxf(d[10], d[11]));
            const float u3 = fmaxf(fmaxf(d[12], d[13]), fmaxf(d[14], d[15]));
            m[jt] = fmaxf(fmaxf(u0, u1), fmaxf(u2, u3));
        }
        float best = fmaxf(fmaxf(m[0], m[1]), fmaxf(m[2], m[3]));
        best = fmaxf(best, __shfl_xor(best, 32));          // fold y halves
        const int x = (xt0 + t)*32 + col;
        if (l < 32 && x < NPTS)
            wsM[((size_t)c*NS + s)*NPTS + x] = best;       // coalesced 128B
        xf = xfn;
    }
}

// ---------------------------------------------------------------------------
// Pass B (R15 verbatim, passed absmax 0.0): 16-lane group per x-point.
//   0) cooperative coalesced LDS stage of the 79x16 slice-max tile
//      (stride-17 -> conflict-free).
//   1) group-max bm of the 79 approx maxima.
//   2) EXACT fp32 rescan of every slice within CAND_EPS of bm (provably
//      contains the winner). Strict > + tie->smaller j == exact
//      first-occurrence argmax.
//   3) lane 0: Welsch + normal terms; block-reduce to float2.
// ---------------------------------------------------------------------------
__global__ __launch_bounds__(256) void finalize(
    const float* __restrict__ pred_pts, const float* __restrict__ pred_nrm,
    const float* __restrict__ targ_pts, const float* __restrict__ targ_nrm,
    const float* __restrict__ wsM, float2* __restrict__ wsB)
{
    const int c   = blockIdx.y;
    const int dir = c >> 1, b = c & 1;
    const float* xp = (dir == 0 ? targ_pts : pred_pts) + (size_t)b * NPTS * 3;
    const float* xn = (dir == 0 ? targ_nrm : pred_nrm) + (size_t)b * NPTS * 3;
    const float* yp = (dir == 0 ? pred_pts : targ_pts) + (size_t)b * NPTS * 3;
    const float* yn = (dir == 0 ? pred_nrm : targ_nrm) + (size_t)b * NPTS * 3;

    const int lane  = threadIdx.x & 15;
    const int xg    = threadIdx.x >> 4;                   // group id: 0..15
    const int n0    = blockIdx.x * 16;
    const int n     = n0 + xg;                            // 625*16 = 10000
    const int gbase = (threadIdx.x & 63) & ~15;           // group base in wave

    __shared__ float sq[NS * 17];                         // stride 17: no conflicts

    for (int i = threadIdx.x; i < NS * 16; i += 256) {
        const int s = i >> 4, g = i & 15;
        sq[s * 17 + g] = wsM[((size_t)c*NS + s)*NPTS + n0 + g];
    }
    __syncthreads();

    float v[5];
    float bm = -1e30f;
#pragma unroll
    for (int k = 0; k < 5; ++k) {
        const int s = lane + 16*k;
        v[k] = (s < NS) ? sq[s * 17 + xg] : -1e30f;
        bm = fmaxf(bm, v[k]);
    }
#pragma unroll
    for (int w = 1; w < 16; w <<= 1)
        bm = fmaxf(bm, __shfl_xor(bm, w, 16));

    const float a  = xp[n*3+0];
    const float bb = xp[n*3+1];
    const float cc = xp[n*3+2];
    const float thr = bm - CAND_EPS;

    float rb  = -1e30f;
    int bidx  = 1 << 30;
#pragma unroll
    for (int k = 0; k < 5; ++k) {
        const unsigned long long full = __ballot(v[k] >= thr);
        unsigned g = (unsigned)((full >> gbase) & 0xFFFFull);
        while (g) {
            const int bpos = __ffs(g) - 1;
            g &= g - 1;
            const int s  = 16*k + bpos;
            const int j0 = s * SLICE;
            const int jend = min(j0 + SLICE, NPTS);
            for (int j = j0 + lane; j < jend; j += 16) {
                const float ya = yp[j*3+0];
                const float yb = yp[j*3+1];
                const float yc = yp[j*3+2];
                const float hy = -0.5f * fmaf(yc, yc, fmaf(yb, yb, ya*ya));
                const float m  = fmaf(a, ya, fmaf(bb, yb, fmaf(cc, yc, hy)));
                if (m > rb || (m == rb && j < bidx)) { rb = m; bidx = j; }
            }
        }
    }
#pragma unroll
    for (int w = 1; w < 16; w <<= 1) {
        const float mo = __shfl_xor(rb, w, 16);
        const int   jo = __shfl_xor(bidx, w, 16);
        if (mo > rb || (mo == rb && jo < bidx)) { rb = mo; bidx = jo; }
    }

    float t0 = 0.f, t1 = 0.f;
    if (lane == 0) {
        const float hx = -0.5f * fmaf(cc, cc, fmaf(bb, bb, a*a));
        float d2 = -2.0f * (rb + hx);
        d2 = fmaxf(d2, 0.0f);
        const float w = __expf(-(d2 * d2) * (1.0f / 0.18f));   // 2*ALPHA^2
        t0 = w * d2;
        const float nx0 = xn[n*3+0], nx1 = xn[n*3+1], nx2 = xn[n*3+2];
        const float ny0 = yn[(size_t)bidx*3+0];
        const float ny1 = yn[(size_t)bidx*3+1];
        const float ny2 = yn[(size_t)bidx*3+2];
        const float nnx = fmaxf(sqrtf(nx0*nx0 + nx1*nx1 + nx2*nx2), 1e-6f);
        const float nny = fmaxf(sqrtf(ny0*ny0 + ny1*ny1 + ny2*ny2), 1e-6f);
        const float cosv = (nx0*ny0 + nx1*ny1 + nx2*ny2) / (nnx * nny);
        t1 = 1.0f - fabsf(cosv);
    }

    __shared__ float r0[256], r1[256];
    r0[threadIdx.x] = t0;
    r1[threadIdx.x] = t1;
    __syncthreads();
    for (int st = 128; st > 0; st >>= 1) {
        if (threadIdx.x < st) {
            r0[threadIdx.x] += r0[threadIdx.x + st];
            r1[threadIdx.x] += r1[threadIdx.x + st];
        }
        __syncthreads();
    }
    if (threadIdx.x == 0)
        wsB[blockIdx.y * gridDim.x + blockIdx.x] = make_float2(r0[0], r1[0]);
}

// ---------------------------------------------------------------------------
// Final deterministic reduction of the 2500 block partials.
// ---------------------------------------------------------------------------
__global__ __launch_bounds__(256) void reduce_final(
    const float2* __restrict__ wsB, int nblocks, float* __restrict__ out)
{
    __shared__ float r0[256], r1[256];
    const int t = threadIdx.x;
    float s0 = 0.f, s1 = 0.f;
    for (int i = t; i < nblocks; i += 256) {
        const float2 v = wsB[i];
        s0 += v.x;
        s1 += v.y;
    }
    r0[t] = s0; r1[t] = s1;
    __syncthreads();
    for (int st = 128; st > 0; st >>= 1) {
        if (t < st) { r0[t] += r0[t + st]; r1[t] += r1[t + st]; }
        __syncthreads();
    }
    if (t == 0) {
        out[0] = 0.5f * r0[0];                 // mean over B=2 of per-batch sums
        out[1] = r1[0] * (1.0f / 20000.0f);    // mean over B*N, both dirs
    }
}

extern "C" void kernel_launch(void* const* d_in, const int* in_sizes, int n_in,
                              void* d_out, int out_size, void* d_ws, size_t ws_size,
                              hipStream_t stream)
{
    const float* pred_pts = (const float*)d_in[0];
    const float* pred_nrm = (const float*)d_in[1];
    const float* targ_pts = (const float*)d_in[2];
    const float* targ_nrm = (const float*)d_in[3];
    float* out = (float*)d_out;

    // workspace carve (~16 MB of ~256 MB)
    unsigned short* ypk = (unsigned short*)d_ws;            // 4*316*512 u16
    unsigned short* xpk = ypk + (size_t)4 * NYT * 512;      // 4*320*512 u16
    float* wsM  = (float*)(xpk + (size_t)4 * NXT2 * 512);   // 4*79*10000 f32
    float2* wsB = (float2*)(wsM + (size_t)4 * NS * NPTS);   // 2500 float2

    const int PTOT = 4 * NYP + 4 * NXT2 * 32;               // pack threads
    pack_xy<<<(PTOT + 255) / 256, 256, 0, stream>>>(pred_pts, targ_pts, ypk, xpk);

    dim3 gA(10, NS, 4);                 // 10 x-groups (32 tiles) x 79 x 4
    knn_mfma<<<gA, 256, 0, stream>>>(ypk, xpk, wsM);

    dim3 gB(NPTS / 16, 4);              // 625 x 4
    finalize<<<gB, 256, 0, stream>>>(pred_pts, pred_nrm, targ_pts, targ_nrm,
                                     wsM, wsB);

    reduce_final<<<1, 256, 0, stream>>>(wsB, (NPTS / 16) * 4, out);
}